// Round 10
// baseline (896.878 us; speedup 1.0000x reference)
//
#include <hip/hip_runtime.h>
#include <hip/hip_bf16.h>
#include <stdint.h>

// QuantizedLinear: out_f32[512,16384] = x_f32[512,4096] @ (qw_i32 * scales)^T + bias
// dtypes (verified round 3): x fp32, qw int32, scales fp32, bias fp32, out fp32.
//
// Round-17: FUSED producer/consumer kernel (wave specialization).
// r16 measurement: gemm = 88us/rep (Mfma 34% ~= m97 ceiling, 0 conflicts,
// FETCH 138MB/rep -> wb re-read from HBM), and by subtraction pack_w ~= 130us.
// The two-stage design's structural cost: qw 256MB + wb write 128MB + wb
// re-read 128MB ~= 512MB HBM vs single-pass minimum 268MB.
// Fix (guide m114 / AITER pattern): one kernel, 640 thr = 8 consumer waves
// (r15's proven m97 consumer loop, untouched) + 2 producer waves that load
// qw int32 coalesced, dequant in-register (scales slab cached in LDS), and
// ds_write bf16 fragments into the next LDS buffer. Dequant VALU runs on
// SEPARATE waves, overlapped with MFMA -- not in the consumer critical path
// (r11's flaw). Barriers: lgkm-only, uniform across roles; producer qw
// prefetch + consumer A prefetch stay in flight across barriers.
// Pipes: qw HBM 43us, LDS ~34us, MFMA 27.5us -> target 70-100us fused.
// pack_w and wb are DELETED. pack_x (4us) kept.

#define MM 512
#define NN 16384
#define KK 4096
#define BN 64
#define BK 128
#define NKB (KK / BK)    // 32
#define NSLAB (NN / BN)  // 256
#define NCTHR 512        // 8 consumer waves
#define NPTHR 128        // 2 producer waves
#define NTHR (NCTHR + NPTHR)

typedef __bf16 bf16x8 __attribute__((ext_vector_type(8)));
typedef float floatx4 __attribute__((ext_vector_type(4)));

__device__ __forceinline__ void barrier_nodrain() {
    // LDS handoff needs lgkmcnt(0); deliberately NO vmcnt drain -- producer
    // qw prefetch and consumer A prefetch stay in flight across the barrier.
    asm volatile("s_waitcnt lgkmcnt(0)\n\ts_barrier" ::: "memory");
}

__device__ __forceinline__ unsigned int pk_bf16_rtn(float lo, float hi) {
    __hip_bfloat162 h = __float22bfloat162_rn(float2{lo, hi});
    return *reinterpret_cast<unsigned int*>(&h);
}

// ---- prepass: x fp32 -> bf16, packed in MFMA A-fragment order ----
// xp element index: (((kb*4 + ks)*32 + mt)*64 + lane)*8,
//   holding x[mt*16 + (lane&15)][kb*128 + ks*32 + (lane>>4)*8 .. +8]
__global__ __launch_bounds__(256) void pack_x(const float* __restrict__ x,
                                              unsigned short* __restrict__ xp) {
    const int t    = blockIdx.x * 256 + threadIdx.x;   // 0..262143
    const int lane = t & 63;
    const int mt   = (t >> 6) & 31;
    const int ks   = (t >> 11) & 3;
    const int kb   = t >> 13;
    const int m    = mt * 16 + (lane & 15);
    const int k    = kb * 128 + ks * 32 + (lane >> 4) * 8;
    const float* px = x + (size_t)m * KK + k;
    const float4 a = *(const float4*)px;
    const float4 b = *(const float4*)(px + 4);
    uint4 o;
    o.x = pk_bf16_rtn(a.x, a.y);
    o.y = pk_bf16_rtn(a.z, a.w);
    o.z = pk_bf16_rtn(b.x, b.y);
    o.w = pk_bf16_rtn(b.z, b.w);
    *(uint4*)(xp + (size_t)t * 8) = o;   // fully coalesced 16B/thread
}

// ---- consumer macros (byte-identical dataflow to r15/r16 gemm) ----
#define LOAD_A(DST, KB)                                                         \
    {                                                                           \
        const unsigned short* ap_ =                                             \
            xp + (size_t)(KB) * 65536                                           \
               + (size_t)((h * 16 + wv * 2) * 64 + lane) * 8;                   \
        _Pragma("unroll")                                                       \
        for (int ks = 0; ks < 4; ++ks) {                                        \
            DST[ks][0] = *(const bf16x8*)(ap_ + ks * 16384);                    \
            DST[ks][1] = *(const bf16x8*)(ap_ + ks * 16384 + 512);              \
        }                                                                       \
    }

#define COMPUTE(BUF, A)                                                         \
    {                                                                           \
        const unsigned short* sb_ = sB[BUF];                                    \
        _Pragma("unroll")                                                       \
        for (int ks = 0; ks < 4; ++ks) {                                        \
            _Pragma("unroll")                                                   \
            for (int jj = 0; jj < 4; jj += 2) {                                 \
                bf16x8 b0 = *(const bf16x8*)(sb_ + ((ks * 4 + jj) * 64 + lane) * 8);     \
                bf16x8 b1 = *(const bf16x8*)(sb_ + ((ks * 4 + jj + 1) * 64 + lane) * 8); \
                acc[0][jj]     = __builtin_amdgcn_mfma_f32_16x16x32_bf16(A[ks][0], b0, acc[0][jj], 0, 0, 0);     \
                acc[1][jj]     = __builtin_amdgcn_mfma_f32_16x16x32_bf16(A[ks][1], b0, acc[1][jj], 0, 0, 0);     \
                acc[0][jj + 1] = __builtin_amdgcn_mfma_f32_16x16x32_bf16(A[ks][0], b1, acc[0][jj + 1], 0, 0, 0); \
                acc[1][jj + 1] = __builtin_amdgcn_mfma_f32_16x16x32_bf16(A[ks][1], b1, acc[1][jj + 1], 0, 0, 0); \
            }                                                                   \
        }                                                                       \
    }

// ---- producer macros ----
// Thread u (0..127) owns chunks c = i*128+u, i=0..15 of the 64x128 tile:
//   row r = i*4 + (u>>5), k-offset kk = (u&31)*4 (elems). Wave covers 64
//   consecutive chunks = 2 contiguous 512B qw row segments -> coalesced.
// Fragment placement (identical to r13-r16 wb layout, verified absmax):
//   ks=kk>>5, q_oct=(kk>>3)&3, e0=kk&7, j=r>>4, l=(q_oct<<4)|(r&15),
//   short idx = ((ks*4+j)*64 + l)*8 + e0  (8B uint2 write).
#define LOADQ(KB)                                                               \
    {                                                                           \
        _Pragma("unroll")                                                       \
        for (int i = 0; i < 16; ++i) {                                          \
            const int r_ = i * 4 + rb;                                          \
            q[i] = *(const int4*)(qbase + (size_t)r_ * KK + (size_t)(KB) * BK); \
        }                                                                       \
    }

#define PRODUCE(KB, BUF)                                                        \
    {                                                                           \
        unsigned short* sw_ = sB[BUF];                                          \
        _Pragma("unroll")                                                       \
        for (int i = 0; i < 16; ++i) {                                          \
            const int r_   = i * 4 + rb;                                        \
            const int sidx = ((ks4 + (r_ >> 4)) * 64 + (qo16 | (r_ & 15))) * 8 + e0; \
            const float s_ = ls[r_][(KB) * 2 + bo];                             \
            uint2 o_;                                                           \
            o_.x = pk_bf16_rtn((float)q[i].x * s_, (float)q[i].y * s_);         \
            o_.y = pk_bf16_rtn((float)q[i].z * s_, (float)q[i].w * s_);         \
            *(uint2*)&sw_[sidx] = o_;                                           \
        }                                                                       \
    }

__global__ __launch_bounds__(NTHR) void qlin_fused(
    const unsigned short* __restrict__ xp,      // packed bf16 x (4 MB)
    const int* __restrict__ qw,                 // int32 [16384,4096]
    const float* __restrict__ scales,           // fp32 [16384,64]
    const float* __restrict__ bias,             // fp32 [16384]
    float* __restrict__ out)                    // fp32 [512,16384]
{
    __shared__ unsigned short sB[2][BN * BK];   // fragment-ordered bf16, 2 x 16 KB
    __shared__ float ls[64][64];                // this slab's scales, 16 KB

    const int t    = threadIdx.x;               // 0..639
    const int slab = blockIdx.x & 255;          // column slab
    const int h    = blockIdx.x >> 8;           // M half
    const int n0   = slab * BN;

    // ---- all threads: cache the slab's scales in LDS ----
    for (int i = t; i < 4096; i += NTHR)
        ls[i >> 6][i & 63] = scales[(size_t)(n0 + (i >> 6)) * 64 + (i & 63)];

    // ---- consumer state ----
    const int lane = t & 63;
    const int wv   = t >> 6;          // waves 0..7 consumers
    const int ln   = lane & 15;
    const int quad = lane >> 4;
    floatx4 acc[2][4];
    bf16x8 aA[4][2], aB[4][2];

    // ---- producer state ----
    const int u    = t - NCTHR;       // 0..127 (valid only for t>=NCTHR)
    const int kk   = (u & 31) * 4;
    const int rb   = u >> 5;
    const int ks4  = (kk >> 5) * 4;           // ks*4
    const int qo16 = ((kk >> 3) & 3) << 4;    // q_oct<<4
    const int e0   = kk & 7;
    const int bo   = kk >> 6;
    const int* qbase = qw + (size_t)n0 * KK + kk;
    int4 q[16];

    if (t >= NCTHR) {
        LOADQ(0)                       // qw tile 0 in flight
    } else {
#pragma unroll
        for (int i = 0; i < 2; ++i)
#pragma unroll
            for (int j = 0; j < 4; ++j)
                acc[i][j] = (floatx4)0.0f;
        LOAD_A(aA, 0)
    }
    barrier_nodrain();                 // B0: ls resident (vmem stays in flight)

    if (t >= NCTHR) {
        PRODUCE(0, 0)                  // waits its own q loads (compiler vmcnt)
        LOADQ(1)
    }
    barrier_nodrain();                 // B1: tile 0 published

    // ---- main loop: 2 iters per pass, uniform barriers ----
    for (int kb = 0; kb < NKB; kb += 2) {
        // even iter: consumers eat (buf0, aA); producers stage kb+1 -> buf1
        if (t < NCTHR) {
            LOAD_A(aB, kb + 1)
            COMPUTE(0, aA)
        } else {
            PRODUCE(kb + 1, 1)
            if (kb + 2 < NKB) LOADQ(kb + 2)
        }
        barrier_nodrain();

        // odd iter: consumers eat (buf1, aB); producers stage kb+2 -> buf0
        if (t < NCTHR) {
            if (kb + 2 < NKB) LOAD_A(aA, kb + 2)
            COMPUTE(1, aB)
        } else {
            if (kb + 2 < NKB) {
                PRODUCE(kb + 2, 0)
                if (kb + 3 < NKB) LOADQ(kb + 3)
            }
        }
        if (kb + 2 < NKB) barrier_nodrain();
    }

    // ---- epilogue: consumers write C (+bias) ----
    if (t < NCTHR) {
#pragma unroll
        for (int j = 0; j < 4; ++j) {
            const int n = n0 + j * 16 + ln;
            const float bv = bias[n];
#pragma unroll
            for (int i = 0; i < 2; ++i) {
                const int mbase = h * 256 + wv * 32 + i * 16 + quad * 4;
#pragma unroll
                for (int rr = 0; rr < 4; ++rr)
                    out[(size_t)(mbase + rr) * NN + n] = acc[i][j][rr] + bv;
            }
        }
    }
}

// ---- fallback (workspace too small; never expected to trigger) ----
__global__ __launch_bounds__(256) void qlin_naive(
    const float* __restrict__ x, const int* __restrict__ qw,
    const float* __restrict__ scales, const float* __restrict__ bias,
    float* __restrict__ out) {
    const int n = blockIdx.x * 256 + threadIdx.x;   // 0..16383
    const int m = blockIdx.y;                       // 0..511
    if (n >= NN || m >= MM) return;
    float accv = 0.0f;
    for (int kb = 0; kb < 64; ++kb) {
        const float s = scales[(size_t)n * 64 + kb];
        float part = 0.0f;
        for (int k = kb * 64; k < kb * 64 + 64; ++k)
            part += x[(size_t)m * KK + k] * (float)qw[(size_t)n * KK + k];
        accv += part * s;
    }
    out[(size_t)m * NN + n] = accv + bias[n];
}

extern "C" void kernel_launch(void* const* d_in, const int* in_sizes, int n_in,
                              void* d_out, int out_size, void* d_ws, size_t ws_size,
                              hipStream_t stream) {
    const float* x    = (const float*)d_in[0];
    const int* qw     = (const int*)d_in[1];
    const float* scl  = (const float*)d_in[2];
    const float* bias = (const float*)d_in[3];
    float* out        = (float*)d_out;

    const size_t XPB = (size_t)MM * KK * sizeof(unsigned short);   // 4 MB

    if (ws_size >= XPB) {
        unsigned short* xp = (unsigned short*)d_ws;
        pack_x<<<dim3(MM * KK / (256 * 8)), dim3(256), 0, stream>>>(x, xp);
        qlin_fused<<<dim3(NSLAB * 2), dim3(NTHR), 0, stream>>>(xp, qw, scl, bias, out);
    } else {
        qlin_naive<<<dim3(NN / 256, MM), dim3(256), 0, stream>>>(x, qw, scl, bias, out);
    }
}